// Round 1
// baseline (61.958 us; speedup 1.0000x reference)
//
#include <hip/hip_runtime.h>
#include <hip/hip_bf16.h>
#include <math.h>

#define V 50257
#define H 1024

// ---------------------------------------------------------------------------
// Kernel 1: fused LSTM step.
// Block k (0..H-1) computes gate rows {k, H+k, 2H+k, 3H+k} of
// gates = w_ih @ e + b_ih + w_hh @ h + b_hh, applies nonlinearities, and
// writes h_new -> out[V+k], c_new -> out[V+H+k].
// 256 threads; thread t covers 4 consecutive floats via float4.
// ---------------------------------------------------------------------------
__global__ __launch_bounds__(256) void lstm_kernel(
    const int* __restrict__ x,
    const float* __restrict__ hidden,
    const float* __restrict__ cell,
    const float* __restrict__ emb,
    const float* __restrict__ w_ih,
    const float* __restrict__ w_hh,
    const float* __restrict__ b_ih,
    const float* __restrict__ b_hh,
    float* __restrict__ out)
{
    const int k = blockIdx.x;
    const int t = threadIdx.x;
    const float* e = emb + (size_t)x[0] * H;

    const int idx = t * 4;  // 256 threads * 4 = 1024 = H
    const float4 ev = *(const float4*)(e + idx);
    const float4 hv = *(const float4*)(hidden + idx);

    float p[8];
#pragma unroll
    for (int g = 0; g < 4; ++g) {
        const float4 wi = *(const float4*)(w_ih + (size_t)(g * H + k) * H + idx);
        const float4 wh = *(const float4*)(w_hh + (size_t)(g * H + k) * H + idx);
        p[2 * g]     = wi.x * ev.x + wi.y * ev.y + wi.z * ev.z + wi.w * ev.w;
        p[2 * g + 1] = wh.x * hv.x + wh.y * hv.y + wh.z * hv.z + wh.w * hv.w;
    }

    // 64-lane wave reduce of all 8 partials
#pragma unroll
    for (int j = 0; j < 8; ++j) {
#pragma unroll
        for (int off = 32; off; off >>= 1)
            p[j] += __shfl_down(p[j], off, 64);
    }

    __shared__ float red[8][4];
    const int wave = t >> 6, lane = t & 63;
    if (lane == 0) {
#pragma unroll
        for (int j = 0; j < 8; ++j) red[j][wave] = p[j];
    }
    __syncthreads();

    if (t == 0) {
        float s[8];
#pragma unroll
        for (int j = 0; j < 8; ++j)
            s[j] = red[j][0] + red[j][1] + red[j][2] + red[j][3];
        const float gi = s[0] + s[1] + b_ih[k]         + b_hh[k];
        const float gf = s[2] + s[3] + b_ih[H + k]     + b_hh[H + k];
        const float gg = s[4] + s[5] + b_ih[2 * H + k] + b_hh[2 * H + k];
        const float go = s[6] + s[7] + b_ih[3 * H + k] + b_hh[3 * H + k];

        const float i_g = 1.0f / (1.0f + expf(-gi));
        const float f_g = 1.0f / (1.0f + expf(-gf));
        const float g_g = tanhf(gg);
        const float o_g = 1.0f / (1.0f + expf(-go));

        const float c_new = f_g * cell[k] + i_g * g_g;
        const float h_new = o_g * tanhf(c_new);

        out[V + k]     = h_new;   // h_new output
        out[V + H + k] = c_new;   // c_new output
    }
}

// ---------------------------------------------------------------------------
// Kernel 2: FC matvec. One 64-lane wave per vocab row; 4 waves per block.
// logits[v] = dot(fc_w[v,:], h_new) + fc_b[v]  -> d_ws
// ---------------------------------------------------------------------------
__global__ __launch_bounds__(256) void fc_kernel(
    const float* __restrict__ fc_w,
    const float* __restrict__ fc_b,
    const float* __restrict__ h_new,   // = out + V
    float* __restrict__ logits)
{
    const int wave = threadIdx.x >> 6;
    const int lane = threadIdx.x & 63;
    const int v = blockIdx.x * 4 + wave;
    if (v >= V) return;

    const float* row = fc_w + (size_t)v * H;
    float acc = 0.0f;
#pragma unroll
    for (int it = 0; it < 4; ++it) {
        const int idx = (it * 64 + lane) * 4;
        const float4 w = *(const float4*)(row + idx);
        const float4 h = *(const float4*)(h_new + idx);
        acc += w.x * h.x + w.y * h.y + w.z * h.z + w.w * h.w;
    }
#pragma unroll
    for (int off = 32; off; off >>= 1)
        acc += __shfl_down(acc, off, 64);

    if (lane == 0) logits[v] = acc + fc_b[v];
}

// ---------------------------------------------------------------------------
// Kernel 3: single-block max + log-sum-exp over the V logits.
// stats[0] = max, stats[1] = log(sum(exp(l - max)))
// ---------------------------------------------------------------------------
__global__ __launch_bounds__(1024) void reduce_kernel(
    const float* __restrict__ logits,
    float* __restrict__ stats)
{
    const int t = threadIdx.x;
    const int wave = t >> 6, lane = t & 63;
    __shared__ float sm[16];
    __shared__ float gmax;

    float m = -INFINITY;
    for (int v = t; v < V; v += 1024) m = fmaxf(m, logits[v]);
#pragma unroll
    for (int off = 32; off; off >>= 1)
        m = fmaxf(m, __shfl_down(m, off, 64));
    if (lane == 0) sm[wave] = m;
    __syncthreads();
    if (t == 0) {
        float mm = sm[0];
#pragma unroll
        for (int i = 1; i < 16; ++i) mm = fmaxf(mm, sm[i]);
        gmax = mm;
    }
    __syncthreads();
    const float M = gmax;

    float s = 0.0f;
    for (int v = t; v < V; v += 1024) s += expf(logits[v] - M);
#pragma unroll
    for (int off = 32; off; off >>= 1)
        s += __shfl_down(s, off, 64);
    if (lane == 0) sm[wave] = s;
    __syncthreads();
    if (t == 0) {
        float ss = 0.0f;
#pragma unroll
        for (int i = 0; i < 16; ++i) ss += sm[i];
        stats[0] = M;
        stats[1] = logf(ss);
    }
}

// ---------------------------------------------------------------------------
// Kernel 4: logp[v] = logits[v] - max - logsumexp
// ---------------------------------------------------------------------------
__global__ __launch_bounds__(256) void logp_kernel(
    const float* __restrict__ logits,
    const float* __restrict__ stats,
    float* __restrict__ out)
{
    const int v = blockIdx.x * 256 + threadIdx.x;
    if (v < V) out[v] = logits[v] - stats[0] - stats[1];
}

extern "C" void kernel_launch(void* const* d_in, const int* in_sizes, int n_in,
                              void* d_out, int out_size, void* d_ws, size_t ws_size,
                              hipStream_t stream)
{
    const int*   x      = (const int*)  d_in[0];
    const float* hidden = (const float*)d_in[1];
    const float* cell   = (const float*)d_in[2];
    const float* emb    = (const float*)d_in[3];
    const float* w_ih   = (const float*)d_in[4];
    const float* w_hh   = (const float*)d_in[5];
    const float* b_ih   = (const float*)d_in[6];
    const float* b_hh   = (const float*)d_in[7];
    const float* fc_w   = (const float*)d_in[8];
    const float* fc_b   = (const float*)d_in[9];
    float* out = (float*)d_out;

    float* logits = (float*)d_ws;            // V floats
    float* stats  = logits + ((V + 63) & ~63); // 2 floats, aligned past logits

    // 1) LSTM step -> out[V .. V+2H)
    lstm_kernel<<<H, 256, 0, stream>>>(x, hidden, cell, emb, w_ih, w_hh,
                                       b_ih, b_hh, out);
    // 2) FC matvec -> logits
    fc_kernel<<<(V + 3) / 4, 256, 0, stream>>>(fc_w, fc_b, out + V, logits);
    // 3) max + logsumexp -> stats
    reduce_kernel<<<1, 1024, 0, stream>>>(logits, stats);
    // 4) normalize -> out[0 .. V)
    logp_kernel<<<(V + 255) / 256, 256, 0, stream>>>(logits, stats, out);
}

// Round 2
// 47.702 us; speedup vs baseline: 1.2989x; 1.2989x over previous
//
#include <hip/hip_runtime.h>
#include <hip/hip_bf16.h>
#include <math.h>

#define V 50257
#define H 1024
#define NB_FC 1024   // blocks in fc kernel; 4 waves each -> 4096 waves

// ---------------------------------------------------------------------------
// Kernel 1: fused LSTM step.
// Block k (0..H-1) computes gate rows {k, H+k, 2H+k, 3H+k} of
// gates = w_ih @ e + b_ih + w_hh @ h + b_hh, applies nonlinearities, and
// writes h_new -> out[V+k], c_new -> out[V+H+k].
// ---------------------------------------------------------------------------
__global__ __launch_bounds__(256) void lstm_kernel(
    const int* __restrict__ x,
    const float* __restrict__ hidden,
    const float* __restrict__ cell,
    const float* __restrict__ emb,
    const float* __restrict__ w_ih,
    const float* __restrict__ w_hh,
    const float* __restrict__ b_ih,
    const float* __restrict__ b_hh,
    float* __restrict__ out)
{
    const int k = blockIdx.x;
    const int t = threadIdx.x;
    const float* e = emb + (size_t)x[0] * H;

    const int idx = t * 4;  // 256 threads * 4 = 1024 = H
    const float4 ev = *(const float4*)(e + idx);
    const float4 hv = *(const float4*)(hidden + idx);

    float p[8];
#pragma unroll
    for (int g = 0; g < 4; ++g) {
        const float4 wi = *(const float4*)(w_ih + (size_t)(g * H + k) * H + idx);
        const float4 wh = *(const float4*)(w_hh + (size_t)(g * H + k) * H + idx);
        p[2 * g]     = wi.x * ev.x + wi.y * ev.y + wi.z * ev.z + wi.w * ev.w;
        p[2 * g + 1] = wh.x * hv.x + wh.y * hv.y + wh.z * hv.z + wh.w * hv.w;
    }

#pragma unroll
    for (int j = 0; j < 8; ++j) {
#pragma unroll
        for (int off = 32; off; off >>= 1)
            p[j] += __shfl_down(p[j], off, 64);
    }

    __shared__ float red[8][4];
    const int wave = t >> 6, lane = t & 63;
    if (lane == 0) {
#pragma unroll
        for (int j = 0; j < 8; ++j) red[j][wave] = p[j];
    }
    __syncthreads();

    if (t == 0) {
        float s[8];
#pragma unroll
        for (int j = 0; j < 8; ++j)
            s[j] = red[j][0] + red[j][1] + red[j][2] + red[j][3];
        const float gi = s[0] + s[1] + b_ih[k]         + b_hh[k];
        const float gf = s[2] + s[3] + b_ih[H + k]     + b_hh[H + k];
        const float gg = s[4] + s[5] + b_ih[2 * H + k] + b_hh[2 * H + k];
        const float go = s[6] + s[7] + b_ih[3 * H + k] + b_hh[3 * H + k];

        const float i_g = 1.0f / (1.0f + expf(-gi));
        const float f_g = 1.0f / (1.0f + expf(-gf));
        const float g_g = tanhf(gg);
        const float o_g = 1.0f / (1.0f + expf(-go));

        const float c_new = f_g * cell[k] + i_g * g_g;
        const float h_new = o_g * tanhf(c_new);

        out[V + k]     = h_new;
        out[V + H + k] = c_new;
    }
}

// ---------------------------------------------------------------------------
// Kernel 2: FC matvec + fused online log-sum-exp partials.
// 4096 waves grid-stride over vocab rows. Each wave: dot(fc_w[v], h_new)
// (h_new hoisted into registers), butterfly all-reduce so every lane has the
// logit, write it, update running (max, sumexp). Block merges 4 wave partials
// -> partials[blockIdx].
// ---------------------------------------------------------------------------
__global__ __launch_bounds__(256) void fc_lse_kernel(
    const float* __restrict__ fc_w,
    const float* __restrict__ fc_b,
    const float* __restrict__ h_new,   // = out + V
    float* __restrict__ logits,
    float2* __restrict__ partials)
{
    const int wave = threadIdx.x >> 6;
    const int lane = threadIdx.x & 63;
    const int wid = blockIdx.x * 4 + wave;
    const int nw = NB_FC * 4;

    float4 hv[4];
#pragma unroll
    for (int it = 0; it < 4; ++it)
        hv[it] = *(const float4*)(h_new + (it * 64 + lane) * 4);

    float m = -INFINITY, s = 0.0f;

    for (int v = wid; v < V; v += nw) {
        const float* row = fc_w + (size_t)v * H;
        float acc = 0.0f;
#pragma unroll
        for (int it = 0; it < 4; ++it) {
            const float4 w = *(const float4*)(row + (it * 64 + lane) * 4);
            acc += w.x * hv[it].x + w.y * hv[it].y + w.z * hv[it].z + w.w * hv[it].w;
        }
#pragma unroll
        for (int off = 1; off < 64; off <<= 1)
            acc += __shfl_xor(acc, off, 64);
        acc += fc_b[v];
        if (lane == 0) logits[v] = acc;

        const float nm = fmaxf(m, acc);
        s = s * __expf(m - nm) + __expf(acc - nm);
        m = nm;
    }

    __shared__ float2 pm[4];
    if (lane == 0) pm[wave] = make_float2(m, s);
    __syncthreads();
    if (threadIdx.x == 0) {
        float M = pm[0].x, S = pm[0].y;
#pragma unroll
        for (int i = 1; i < 4; ++i) {
            const float m2 = pm[i].x, s2 = pm[i].y;
            const float nM = fmaxf(M, m2);
            S = S * __expf(M - nM) + s2 * __expf(m2 - nM);
            M = nM;
        }
        partials[blockIdx.x] = make_float2(M, S);
    }
}

// ---------------------------------------------------------------------------
// Kernel 3: each block redundantly merges the 1024 (m,s) partials (identical
// deterministic result), then normalizes its slice of the logits.
// Grid: ceil(V/1024) blocks of 256 threads; 4 outputs per thread.
// ---------------------------------------------------------------------------
__global__ __launch_bounds__(256) void logp_kernel(
    const float* __restrict__ logits,
    const float2* __restrict__ partials,
    float* __restrict__ out)
{
    const int t = threadIdx.x;
    const int lane = t & 63;
    const int wave = t >> 6;

    float m = -INFINITY, s = 0.0f;
#pragma unroll
    for (int i = 0; i < 4; ++i) {
        const float2 p = partials[t * 4 + i];
        const float nm = fmaxf(m, p.x);
        s = s * __expf(m - nm) + p.y * __expf(p.x - nm);
        m = nm;
    }
#pragma unroll
    for (int off = 1; off < 64; off <<= 1) {
        const float om = __shfl_xor(m, off, 64);
        const float os = __shfl_xor(s, off, 64);
        const float nm = fmaxf(m, om);
        s = s * __expf(m - nm) + os * __expf(om - nm);
        m = nm;
    }
    __shared__ float2 red[4];
    __shared__ float sub_s;
    if (lane == 0) red[wave] = make_float2(m, s);
    __syncthreads();
    if (t == 0) {
        float M = red[0].x, S = red[0].y;
#pragma unroll
        for (int i = 1; i < 4; ++i) {
            const float nm2 = fmaxf(M, red[i].x);
            S = S * __expf(M - nm2) + red[i].y * __expf(red[i].x - nm2);
            M = nm2;
        }
        sub_s = M + logf(S);
    }
    __syncthreads();
    const float sub = sub_s;

    const int base = (blockIdx.x * 256 + t) * 4;
#pragma unroll
    for (int j = 0; j < 4; ++j) {
        const int v = base + j;
        if (v < V) out[v] = logits[v] - sub;
    }
}

extern "C" void kernel_launch(void* const* d_in, const int* in_sizes, int n_in,
                              void* d_out, int out_size, void* d_ws, size_t ws_size,
                              hipStream_t stream)
{
    const int*   x      = (const int*)  d_in[0];
    const float* hidden = (const float*)d_in[1];
    const float* cell   = (const float*)d_in[2];
    const float* emb    = (const float*)d_in[3];
    const float* w_ih   = (const float*)d_in[4];
    const float* w_hh   = (const float*)d_in[5];
    const float* b_ih   = (const float*)d_in[6];
    const float* b_hh   = (const float*)d_in[7];
    const float* fc_w   = (const float*)d_in[8];
    const float* fc_b   = (const float*)d_in[9];
    float* out = (float*)d_out;

    float*  logits   = (float*)d_ws;                    // V floats
    float2* partials = (float2*)(logits + ((V + 255) & ~255)); // NB_FC float2

    // 1) LSTM step -> out[V .. V+2H)
    lstm_kernel<<<H, 256, 0, stream>>>(x, hidden, cell, emb, w_ih, w_hh,
                                       b_ih, b_hh, out);
    // 2) FC matvec + LSE partials
    fc_lse_kernel<<<NB_FC, 256, 0, stream>>>(fc_w, fc_b, out + V, logits, partials);
    // 3) merge partials (redundant per block) + normalize -> out[0 .. V)
    logp_kernel<<<(V + 1023) / 1024, 256, 0, stream>>>(logits, partials, out);
}